// Round 1
// baseline (4056.243 us; speedup 1.0000x reference)
//
#include <hip/hip_runtime.h>
#include <hip/hip_bf16.h>

#define DD 64
#define HH 128

// ---------------------------------------------------------------------------
// Edge kernel: 16 edges per 256-thread block.
//   xT[k][e] staged in LDS (k-major, +1 pad), W streamed from global (L2-hot).
//   Thread t: edge e = t&15, hidden cols j0..j0+7 (j0 = (t>>4)*8).
//   Writes out_e = mlp + ef (residual), atomically accumulates agg[dst], deg,
//   and a block-reduced edge_sum for the global readout.
// ---------------------------------------------------------------------------
__global__ __launch_bounds__(256) void edge_kernel(
    const float* __restrict__ nf, const float* __restrict__ ef,
    const float* __restrict__ u,
    const float* __restrict__ W1, const float* __restrict__ b1,
    const float* __restrict__ W2, const float* __restrict__ b2,
    const int* __restrict__ src, const int* __restrict__ dst,
    float* __restrict__ out_e,
    float* __restrict__ agg, float* __restrict__ deg,
    float* __restrict__ edge_sum,
    int E)
{
    __shared__ float xT[256][17];
    __shared__ float hT[128][17];
    __shared__ float ssum[64];

    const int tid = threadIdx.x;
    const int e0  = blockIdx.x * 16;

    // stage inputs: thread tid loads column k=tid for each of 16 edges
    for (int i = tid; i < 16 * 256; i += 256) {
        int e = i >> 8;
        int k = i & 255;
        int ge = e0 + e;
        float v = 0.f;
        if (ge < E) {
            if (k < 64)       v = nf[(size_t)src[ge] * 64 + k];
            else if (k < 128) v = nf[(size_t)dst[ge] * 64 + (k - 64)];
            else if (k < 192) v = ef[(size_t)ge * 64 + (k - 128)];
            else              v = u[k - 192];
        }
        xT[k][e] = v;
    }
    if (tid < 64) ssum[tid] = 0.f;
    __syncthreads();

    const int e  = tid & 15;
    const int jg = tid >> 4;      // 0..15
    const int j0 = jg * 8;

    // layer 1: [256] -> [128], thread computes 8 hidden cols for its edge
    float acc[8];
#pragma unroll
    for (int i = 0; i < 8; ++i) acc[i] = b1[j0 + i];
#pragma unroll 4
    for (int k = 0; k < 256; ++k) {
        float xv = xT[k][e];
        float4 w0 = *reinterpret_cast<const float4*>(&W1[k * HH + j0]);
        float4 w1 = *reinterpret_cast<const float4*>(&W1[k * HH + j0 + 4]);
        acc[0] = fmaf(xv, w0.x, acc[0]);
        acc[1] = fmaf(xv, w0.y, acc[1]);
        acc[2] = fmaf(xv, w0.z, acc[2]);
        acc[3] = fmaf(xv, w0.w, acc[3]);
        acc[4] = fmaf(xv, w1.x, acc[4]);
        acc[5] = fmaf(xv, w1.y, acc[5]);
        acc[6] = fmaf(xv, w1.z, acc[6]);
        acc[7] = fmaf(xv, w1.w, acc[7]);
    }
#pragma unroll
    for (int i = 0; i < 8; ++i) hT[j0 + i][e] = fmaxf(acc[i], 0.f);
    __syncthreads();

    // layer 2: [128] -> [64], thread computes 4 out cols for its edge
    const int o0 = jg * 4;
    float acc2[4];
#pragma unroll
    for (int i = 0; i < 4; ++i) acc2[i] = b2[o0 + i];
#pragma unroll 4
    for (int k = 0; k < 128; ++k) {
        float hv = hT[k][e];
        float4 w = *reinterpret_cast<const float4*>(&W2[k * DD + o0]);
        acc2[0] = fmaf(hv, w.x, acc2[0]);
        acc2[1] = fmaf(hv, w.y, acc2[1]);
        acc2[2] = fmaf(hv, w.z, acc2[2]);
        acc2[3] = fmaf(hv, w.w, acc2[3]);
    }

    int ge = e0 + e;
    if (ge < E) {
        size_t base = (size_t)ge * 64 + o0;
        float4 r = *reinterpret_cast<const float4*>(&ef[base]);
        float4 o;
        o.x = acc2[0] + r.x; o.y = acc2[1] + r.y;
        o.z = acc2[2] + r.z; o.w = acc2[3] + r.w;
        *reinterpret_cast<float4*>(&out_e[base]) = o;

        int d = dst[ge];
#pragma unroll
        for (int i = 0; i < 4; ++i) {
            atomicAdd(&agg[(size_t)d * 64 + o0 + i], acc2[i]);  // pre-residual
            atomicAdd(&ssum[o0 + i], acc2[i]);
        }
        if (jg == 0) atomicAdd(&deg[d], 1.0f);
    }
    __syncthreads();
    if (tid < 64) atomicAdd(&edge_sum[tid], ssum[tid]);
}

// ---------------------------------------------------------------------------
// Node kernel: 16 nodes per 256-thread block. K = 192 (agg_m | nf | u).
// ---------------------------------------------------------------------------
__global__ __launch_bounds__(256) void node_kernel(
    const float* __restrict__ nf, const float* __restrict__ u,
    const float* __restrict__ W1, const float* __restrict__ b1,
    const float* __restrict__ W2, const float* __restrict__ b2,
    const float* __restrict__ agg, const float* __restrict__ deg,
    float* __restrict__ out_n, float* __restrict__ node_sum,
    int N)
{
    __shared__ float xT[192][17];
    __shared__ float hT[128][17];
    __shared__ float ssum[64];

    const int tid = threadIdx.x;
    const int n0  = blockIdx.x * 16;

    for (int i = tid; i < 16 * 192; i += 256) {
        int e = i / 192;
        int k = i - e * 192;
        int gn = n0 + e;
        float v = 0.f;
        if (gn < N) {
            if (k < 64)       v = agg[(size_t)gn * 64 + k] / fmaxf(deg[gn], 1.0f);
            else if (k < 128) v = nf[(size_t)gn * 64 + (k - 64)];
            else              v = u[k - 128];
        }
        xT[k][e] = v;
    }
    if (tid < 64) ssum[tid] = 0.f;
    __syncthreads();

    const int e  = tid & 15;
    const int jg = tid >> 4;
    const int j0 = jg * 8;

    float acc[8];
#pragma unroll
    for (int i = 0; i < 8; ++i) acc[i] = b1[j0 + i];
#pragma unroll 4
    for (int k = 0; k < 192; ++k) {
        float xv = xT[k][e];
        float4 w0 = *reinterpret_cast<const float4*>(&W1[k * HH + j0]);
        float4 w1 = *reinterpret_cast<const float4*>(&W1[k * HH + j0 + 4]);
        acc[0] = fmaf(xv, w0.x, acc[0]);
        acc[1] = fmaf(xv, w0.y, acc[1]);
        acc[2] = fmaf(xv, w0.z, acc[2]);
        acc[3] = fmaf(xv, w0.w, acc[3]);
        acc[4] = fmaf(xv, w1.x, acc[4]);
        acc[5] = fmaf(xv, w1.y, acc[5]);
        acc[6] = fmaf(xv, w1.z, acc[6]);
        acc[7] = fmaf(xv, w1.w, acc[7]);
    }
#pragma unroll
    for (int i = 0; i < 8; ++i) hT[j0 + i][e] = fmaxf(acc[i], 0.f);
    __syncthreads();

    const int o0 = jg * 4;
    float acc2[4];
#pragma unroll
    for (int i = 0; i < 4; ++i) acc2[i] = b2[o0 + i];
#pragma unroll 4
    for (int k = 0; k < 128; ++k) {
        float hv = hT[k][e];
        float4 w = *reinterpret_cast<const float4*>(&W2[k * DD + o0]);
        acc2[0] = fmaf(hv, w.x, acc2[0]);
        acc2[1] = fmaf(hv, w.y, acc2[1]);
        acc2[2] = fmaf(hv, w.z, acc2[2]);
        acc2[3] = fmaf(hv, w.w, acc2[3]);
    }

    int gn = n0 + e;
    if (gn < N) {
        size_t base = (size_t)gn * 64 + o0;
        float4 r = *reinterpret_cast<const float4*>(&nf[base]);
        float4 o;
        o.x = acc2[0] + r.x; o.y = acc2[1] + r.y;
        o.z = acc2[2] + r.z; o.w = acc2[3] + r.w;
        *reinterpret_cast<float4*>(&out_n[base]) = o;
#pragma unroll
        for (int i = 0; i < 4; ++i) atomicAdd(&ssum[o0 + i], acc2[i]);
    }
    __syncthreads();
    if (tid < 64) atomicAdd(&node_sum[tid], ssum[tid]);
}

// ---------------------------------------------------------------------------
// Global kernel: single block, 128 threads. gm = [node_mean | edge_mean | u].
// ---------------------------------------------------------------------------
__global__ __launch_bounds__(128) void global_kernel(
    const float* __restrict__ u,
    const float* __restrict__ W1, const float* __restrict__ b1,
    const float* __restrict__ W2, const float* __restrict__ b2,
    const float* __restrict__ node_sum, const float* __restrict__ edge_sum,
    float* __restrict__ out_u, int N, int E)
{
    __shared__ float gm[192];
    __shared__ float h[128];
    int tid = threadIdx.x;
    if (tid < 64) {
        gm[tid]       = node_sum[tid] / (float)N;
        gm[64 + tid]  = edge_sum[tid] / (float)E;
        gm[128 + tid] = u[tid];
    }
    __syncthreads();
    float a = b1[tid];
    for (int k = 0; k < 192; ++k) a = fmaf(gm[k], W1[k * HH + tid], a);
    h[tid] = fmaxf(a, 0.f);
    __syncthreads();
    if (tid < 64) {
        float o = b2[tid];
        for (int k = 0; k < 128; ++k) o = fmaf(h[k], W2[k * DD + tid], o);
        out_u[tid] = o + u[tid];
    }
}

extern "C" void kernel_launch(void* const* d_in, const int* in_sizes, int n_in,
                              void* d_out, int out_size, void* d_ws, size_t ws_size,
                              hipStream_t stream) {
    const float* nf  = (const float*)d_in[0];
    const float* ef  = (const float*)d_in[1];
    const float* u   = (const float*)d_in[2];
    const float* eW1 = (const float*)d_in[3];
    const float* eb1 = (const float*)d_in[4];
    const float* eW2 = (const float*)d_in[5];
    const float* eb2 = (const float*)d_in[6];
    const float* nW1 = (const float*)d_in[7];
    const float* nb1 = (const float*)d_in[8];
    const float* nW2 = (const float*)d_in[9];
    const float* nb2 = (const float*)d_in[10];
    const float* gW1 = (const float*)d_in[11];
    const float* gb1 = (const float*)d_in[12];
    const float* gW2 = (const float*)d_in[13];
    const float* gb2 = (const float*)d_in[14];
    const int*   src = (const int*)d_in[15];
    const int*   dst = (const int*)d_in[16];

    const int N = in_sizes[0] / 64;
    const int E = in_sizes[1] / 64;

    // workspace layout (floats): agg[N*64] | deg[N] | edge_sum[64] | node_sum[64]
    float* agg      = (float*)d_ws;
    float* deg      = agg + (size_t)N * 64;
    float* edge_sum = deg + N;
    float* node_sum = edge_sum + 64;
    size_t ws_used  = ((size_t)N * 64 + N + 128) * sizeof(float);
    hipMemsetAsync(d_ws, 0, ws_used, stream);

    float* out_n = (float*)d_out;
    float* out_e = out_n + (size_t)N * 64;
    float* out_u = out_e + (size_t)E * 64;

    edge_kernel<<<(E + 15) / 16, 256, 0, stream>>>(
        nf, ef, u, eW1, eb1, eW2, eb2, src, dst, out_e, agg, deg, edge_sum, E);
    node_kernel<<<(N + 15) / 16, 256, 0, stream>>>(
        nf, u, nW1, nb1, nW2, nb2, agg, deg, out_n, node_sum, N);
    global_kernel<<<1, 128, 0, stream>>>(
        u, gW1, gb1, gW2, gb2, node_sum, edge_sum, out_u, N, E);
}

// Round 2
// 566.764 us; speedup vs baseline: 7.1569x; 7.1569x over previous
//
#include <hip/hip_runtime.h>
#include <hip/hip_bf16.h>

typedef __bf16 bf16x8 __attribute__((ext_vector_type(8)));
typedef __bf16 bf16x4 __attribute__((ext_vector_type(4)));
typedef float  f32x4  __attribute__((ext_vector_type(4)));

#define SWZ(row, byte) ((byte) ^ (((row) & 15) << 4))

// ---------------------------------------------------------------------------
// prep: nf f32 -> bf16 (vectorized x4)
// ---------------------------------------------------------------------------
__global__ __launch_bounds__(256) void prep_nf(const float* __restrict__ nf,
                                               __bf16* __restrict__ nfb, int n) {
    int i = (blockIdx.x * 256 + threadIdx.x) * 4;
    if (i < n) {
        float4 v = *reinterpret_cast<const float4*>(nf + i);
        bf16x4 o;
        o[0] = (__bf16)v.x; o[1] = (__bf16)v.y; o[2] = (__bf16)v.z; o[3] = (__bf16)v.w;
        *reinterpret_cast<bf16x4*>(nfb + i) = o;
    }
}

// ---------------------------------------------------------------------------
// prep: weights -> bf16, transposed to [n][k] so B-fragments are contiguous
// ---------------------------------------------------------------------------
__global__ __launch_bounds__(256) void prep_w(
    const float* __restrict__ eW1, const float* __restrict__ eW2,
    const float* __restrict__ nW1, const float* __restrict__ nW2,
    const float* __restrict__ u,
    __bf16* __restrict__ wt1e, __bf16* __restrict__ wt2e,
    __bf16* __restrict__ wt1n, __bf16* __restrict__ wt2n,
    __bf16* __restrict__ ub) {
    int i = blockIdx.x * 256 + threadIdx.x;
    if (i < 32768) {                       // eW1 [256][128] -> [128][256]
        int n = i >> 8, k = i & 255;
        wt1e[i] = (__bf16)eW1[k * 128 + n];
    } else if (i < 40960) {                // eW2 [128][64] -> [64][128]
        int j = i - 32768; int n = j >> 7, k = j & 127;
        wt2e[j] = (__bf16)eW2[k * 64 + n];
    } else if (i < 65536) {                // nW1 [192][128] -> [128][192]
        int j = i - 40960; int n = j / 192, k = j - n * 192;
        wt1n[j] = (__bf16)nW1[k * 128 + n];
    } else if (i < 73728) {                // nW2 [128][64] -> [64][128]
        int j = i - 65536; int n = j >> 7, k = j & 127;
        wt2n[j] = (__bf16)nW2[k * 64 + n];
    } else if (i < 73792) {
        ub[i - 73728] = (__bf16)u[i - 73728];
    }
}

// ---------------------------------------------------------------------------
// Edge MLP, MFMA. 128 edges/block, 4 waves x 32 edges, all-register GEMM.
// A-frag: row = lane&15 (edge), k = (lane>>4)*8+i  (gathered from nfb/ef/ub)
// B-frag: col = lane&15, k = (lane>>4)*8+i          (WT row-major [n][k])
// D:      col = lane&15, row = (lane>>4)*4+r
// Layer1->Layer2 handoff via per-wave 8KB XOR-swizzled bf16 LDS tile.
// ---------------------------------------------------------------------------
__global__ __launch_bounds__(256) void edge_mfma(
    const float* __restrict__ ef,
    const __bf16* __restrict__ nfb, const __bf16* __restrict__ ub,
    const __bf16* __restrict__ wt1, const __bf16* __restrict__ wt2,
    const float* __restrict__ b1, const float* __restrict__ b2,
    const int* __restrict__ src, const int* __restrict__ dst,
    float* __restrict__ out_e, float* __restrict__ agg, float* __restrict__ deg,
    int E)
{
    __shared__ alignas(16) char h_lds[4][8192];
    const int tid = threadIdx.x;
    const int w = tid >> 6, l = tid & 63;
    const int lo = l & 15, hi = l >> 4;
    char* hp = h_lds[w];
    const long eb = (long)blockIdx.x * 128 + w * 32;

    int geA[2], srcA[2], dstA[2];
#pragma unroll
    for (int mt = 0; mt < 2; ++mt) {
        long ge = eb + mt * 16 + lo;
        geA[mt] = (ge < E) ? (int)ge : 0;
        srcA[mt] = src[geA[mt]];
        dstA[mt] = dst[geA[mt]];
    }
    float b1v[8];
#pragma unroll
    for (int nt = 0; nt < 8; ++nt) b1v[nt] = b1[nt * 16 + lo];
    float b2v[4];
#pragma unroll
    for (int nt = 0; nt < 4; ++nt) b2v[nt] = b2[nt * 16 + lo];

    f32x4 acc1[2][8] = {};
#pragma unroll
    for (int kk = 0; kk < 8; ++kk) {               // K = 256
        const int koff = (kk & 1) * 32 + hi * 8;
        bf16x8 bfr[8];
#pragma unroll
        for (int nt = 0; nt < 8; ++nt)
            bfr[nt] = *(const bf16x8*)(wt1 + (nt * 16 + lo) * 256 + kk * 32 + hi * 8);
        bf16x8 afr[2];
        const int sec = kk >> 1;                   // section uniform per kk
#pragma unroll
        for (int mt = 0; mt < 2; ++mt) {
            if (sec == 0) {
                afr[mt] = *(const bf16x8*)(nfb + (size_t)srcA[mt] * 64 + koff);
            } else if (sec == 1) {
                afr[mt] = *(const bf16x8*)(nfb + (size_t)dstA[mt] * 64 + koff);
            } else if (sec == 2) {
                const float* p = ef + (size_t)geA[mt] * 64 + koff;
                float4 v0 = *(const float4*)p;
                float4 v1 = *(const float4*)(p + 4);
                bf16x8 t;
                t[0] = (__bf16)v0.x; t[1] = (__bf16)v0.y; t[2] = (__bf16)v0.z; t[3] = (__bf16)v0.w;
                t[4] = (__bf16)v1.x; t[5] = (__bf16)v1.y; t[6] = (__bf16)v1.z; t[7] = (__bf16)v1.w;
                afr[mt] = t;
            } else {
                afr[mt] = *(const bf16x8*)(ub + koff);
            }
        }
#pragma unroll
        for (int mt = 0; mt < 2; ++mt)
#pragma unroll
            for (int nt = 0; nt < 8; ++nt)
                acc1[mt][nt] = __builtin_amdgcn_mfma_f32_16x16x32_bf16(
                    afr[mt], bfr[nt], acc1[mt][nt], 0, 0, 0);
    }

    // h = relu(acc1 + b1) -> per-wave LDS (bf16, XOR-swizzled rows)
#pragma unroll
    for (int mt = 0; mt < 2; ++mt)
#pragma unroll
        for (int nt = 0; nt < 8; ++nt) {
            int col = nt * 16 + lo;
#pragma unroll
            for (int r = 0; r < 4; ++r) {
                int row = mt * 16 + hi * 4 + r;
                float hv = fmaxf(acc1[mt][nt][r] + b1v[nt], 0.0f);
                *(__bf16*)(hp + SWZ(row, row * 256 + col * 2)) = (__bf16)hv;
            }
        }
    __syncthreads();

    f32x4 acc2[2][4] = {};
#pragma unroll
    for (int kk = 0; kk < 4; ++kk) {               // K = 128
        bf16x8 bfr[4];
#pragma unroll
        for (int nt = 0; nt < 4; ++nt)
            bfr[nt] = *(const bf16x8*)(wt2 + (nt * 16 + lo) * 128 + kk * 32 + hi * 8);
        bf16x8 afr[2];
#pragma unroll
        for (int mt = 0; mt < 2; ++mt) {
            int row = mt * 16 + lo;
            afr[mt] = *(const bf16x8*)(hp + SWZ(row, row * 256 + (kk * 32 + hi * 8) * 2));
        }
#pragma unroll
        for (int mt = 0; mt < 2; ++mt)
#pragma unroll
            for (int nt = 0; nt < 4; ++nt)
                acc2[mt][nt] = __builtin_amdgcn_mfma_f32_16x16x32_bf16(
                    afr[mt], bfr[nt], acc2[mt][nt], 0, 0, 0);
    }

    // epilogue: residual store + agg atomics + deg
#pragma unroll
    for (int mt = 0; mt < 2; ++mt)
#pragma unroll
        for (int r = 0; r < 4; ++r) {
            long ge = eb + mt * 16 + hi * 4 + r;
            if (ge >= E) continue;
            int gei = (int)ge;
            int d = dst[gei];
#pragma unroll
            for (int nt = 0; nt < 4; ++nt) {
                int col = nt * 16 + lo;
                float msg = acc2[mt][nt][r] + b2v[nt];
                out_e[(size_t)gei * 64 + col] = msg + ef[(size_t)gei * 64 + col];
                atomicAdd(&agg[(size_t)d * 64 + col], msg);
            }
            if (lo == 0) atomicAdd(&deg[d], 1.0f);
        }
}

// ---------------------------------------------------------------------------
// Node MLP, MFMA. Same structure, K = 192 (agg/deg | nf | u).
// ---------------------------------------------------------------------------
__global__ __launch_bounds__(256) void node_mfma(
    const float* __restrict__ nf,
    const __bf16* __restrict__ nfb, const __bf16* __restrict__ ub,
    const __bf16* __restrict__ wt1, const __bf16* __restrict__ wt2,
    const float* __restrict__ b1, const float* __restrict__ b2,
    const float* __restrict__ agg, const float* __restrict__ deg,
    float* __restrict__ out_n, float* __restrict__ node_sum,
    int N)
{
    __shared__ alignas(16) char h_lds[4][8192];
    const int tid = threadIdx.x;
    const int w = tid >> 6, l = tid & 63;
    const int lo = l & 15, hi = l >> 4;
    char* hp = h_lds[w];
    const long nb = (long)blockIdx.x * 128 + w * 32;

    int gnA[2]; float inv[2];
#pragma unroll
    for (int mt = 0; mt < 2; ++mt) {
        long gn = nb + mt * 16 + lo;
        gnA[mt] = (gn < N) ? (int)gn : 0;
        inv[mt] = 1.0f / fmaxf(deg[gnA[mt]], 1.0f);
    }
    float b1v[8];
#pragma unroll
    for (int nt = 0; nt < 8; ++nt) b1v[nt] = b1[nt * 16 + lo];
    float b2v[4];
#pragma unroll
    for (int nt = 0; nt < 4; ++nt) b2v[nt] = b2[nt * 16 + lo];

    f32x4 acc1[2][8] = {};
#pragma unroll
    for (int kk = 0; kk < 6; ++kk) {               // K = 192
        const int koff = (kk & 1) * 32 + hi * 8;
        bf16x8 bfr[8];
#pragma unroll
        for (int nt = 0; nt < 8; ++nt)
            bfr[nt] = *(const bf16x8*)(wt1 + (nt * 16 + lo) * 192 + kk * 32 + hi * 8);
        bf16x8 afr[2];
        const int sec = kk >> 1;
#pragma unroll
        for (int mt = 0; mt < 2; ++mt) {
            if (sec == 0) {
                const float* p = agg + (size_t)gnA[mt] * 64 + koff;
                float4 v0 = *(const float4*)p;
                float4 v1 = *(const float4*)(p + 4);
                bf16x8 t;
                t[0] = (__bf16)(v0.x * inv[mt]); t[1] = (__bf16)(v0.y * inv[mt]);
                t[2] = (__bf16)(v0.z * inv[mt]); t[3] = (__bf16)(v0.w * inv[mt]);
                t[4] = (__bf16)(v1.x * inv[mt]); t[5] = (__bf16)(v1.y * inv[mt]);
                t[6] = (__bf16)(v1.z * inv[mt]); t[7] = (__bf16)(v1.w * inv[mt]);
                afr[mt] = t;
            } else if (sec == 1) {
                afr[mt] = *(const bf16x8*)(nfb + (size_t)gnA[mt] * 64 + koff);
            } else {
                afr[mt] = *(const bf16x8*)(ub + koff);
            }
        }
#pragma unroll
        for (int mt = 0; mt < 2; ++mt)
#pragma unroll
            for (int nt = 0; nt < 8; ++nt)
                acc1[mt][nt] = __builtin_amdgcn_mfma_f32_16x16x32_bf16(
                    afr[mt], bfr[nt], acc1[mt][nt], 0, 0, 0);
    }

#pragma unroll
    for (int mt = 0; mt < 2; ++mt)
#pragma unroll
        for (int nt = 0; nt < 8; ++nt) {
            int col = nt * 16 + lo;
#pragma unroll
            for (int r = 0; r < 4; ++r) {
                int row = mt * 16 + hi * 4 + r;
                float hv = fmaxf(acc1[mt][nt][r] + b1v[nt], 0.0f);
                *(__bf16*)(hp + SWZ(row, row * 256 + col * 2)) = (__bf16)hv;
            }
        }
    __syncthreads();

    f32x4 acc2[2][4] = {};
#pragma unroll
    for (int kk = 0; kk < 4; ++kk) {
        bf16x8 bfr[4];
#pragma unroll
        for (int nt = 0; nt < 4; ++nt)
            bfr[nt] = *(const bf16x8*)(wt2 + (nt * 16 + lo) * 128 + kk * 32 + hi * 8);
        bf16x8 afr[2];
#pragma unroll
        for (int mt = 0; mt < 2; ++mt) {
            int row = mt * 16 + lo;
            afr[mt] = *(const bf16x8*)(hp + SWZ(row, row * 256 + (kk * 32 + hi * 8) * 2));
        }
#pragma unroll
        for (int mt = 0; mt < 2; ++mt)
#pragma unroll
            for (int nt = 0; nt < 4; ++nt)
                acc2[mt][nt] = __builtin_amdgcn_mfma_f32_16x16x32_bf16(
                    afr[mt], bfr[nt], acc2[mt][nt], 0, 0, 0);
    }

    float nsum[4] = {0.f, 0.f, 0.f, 0.f};
#pragma unroll
    for (int mt = 0; mt < 2; ++mt)
#pragma unroll
        for (int r = 0; r < 4; ++r) {
            long gn = nb + mt * 16 + hi * 4 + r;
            if (gn >= N) continue;
            int gni = (int)gn;
#pragma unroll
            for (int nt = 0; nt < 4; ++nt) {
                int col = nt * 16 + lo;
                float msg = acc2[mt][nt][r] + b2v[nt];
                out_n[(size_t)gni * 64 + col] = msg + nf[(size_t)gni * 64 + col];
                nsum[nt] += msg;
            }
        }
#pragma unroll
    for (int nt = 0; nt < 4; ++nt) {
        float v = nsum[nt];
        v += __shfl_xor(v, 16);
        v += __shfl_xor(v, 32);
        if (l < 16) atomicAdd(&node_sum[nt * 16 + l], v);
    }
}

// ---------------------------------------------------------------------------
// edge_sum[c] = sum_d agg[d][c]
// ---------------------------------------------------------------------------
__global__ __launch_bounds__(256) void reduce_agg(const float* __restrict__ agg,
                                                  float* __restrict__ edge_sum, int N) {
    int col = threadIdx.x & 63;
    int rbase = blockIdx.x * 4 + (threadIdx.x >> 6);
    float s = 0.f;
    for (int r = rbase; r < N; r += gridDim.x * 4)
        s += agg[(size_t)r * 64 + col];
    __shared__ float sm[256];
    sm[threadIdx.x] = s;
    __syncthreads();
    if (threadIdx.x < 64) {
        float v = sm[threadIdx.x] + sm[threadIdx.x + 64] + sm[threadIdx.x + 128] + sm[threadIdx.x + 192];
        atomicAdd(&edge_sum[threadIdx.x], v);
    }
}

// ---------------------------------------------------------------------------
// Global MLP: single block.
// ---------------------------------------------------------------------------
__global__ __launch_bounds__(128) void global_kernel(
    const float* __restrict__ u,
    const float* __restrict__ W1, const float* __restrict__ b1,
    const float* __restrict__ W2, const float* __restrict__ b2,
    const float* __restrict__ node_sum, const float* __restrict__ edge_sum,
    float* __restrict__ out_u, int N, int E)
{
    __shared__ float gm[192];
    __shared__ float h[128];
    int tid = threadIdx.x;
    if (tid < 64) {
        gm[tid]       = node_sum[tid] / (float)N;
        gm[64 + tid]  = edge_sum[tid] / (float)E;
        gm[128 + tid] = u[tid];
    }
    __syncthreads();
    float a = b1[tid];
    for (int k = 0; k < 192; ++k) a = fmaf(gm[k], W1[k * 128 + tid], a);
    h[tid] = fmaxf(a, 0.f);
    __syncthreads();
    if (tid < 64) {
        float o = b2[tid];
        for (int k = 0; k < 128; ++k) o = fmaf(h[k], W2[k * 64 + tid], o);
        out_u[tid] = o + u[tid];
    }
}

extern "C" void kernel_launch(void* const* d_in, const int* in_sizes, int n_in,
                              void* d_out, int out_size, void* d_ws, size_t ws_size,
                              hipStream_t stream) {
    const float* nf  = (const float*)d_in[0];
    const float* ef  = (const float*)d_in[1];
    const float* u   = (const float*)d_in[2];
    const float* eW1 = (const float*)d_in[3];
    const float* eb1 = (const float*)d_in[4];
    const float* eW2 = (const float*)d_in[5];
    const float* eb2 = (const float*)d_in[6];
    const float* nW1 = (const float*)d_in[7];
    const float* nb1 = (const float*)d_in[8];
    const float* nW2 = (const float*)d_in[9];
    const float* nb2 = (const float*)d_in[10];
    const float* gW1 = (const float*)d_in[11];
    const float* gb1 = (const float*)d_in[12];
    const float* gW2 = (const float*)d_in[13];
    const float* gb2 = (const float*)d_in[14];
    const int*   src = (const int*)d_in[15];
    const int*   dst = (const int*)d_in[16];

    const int N = in_sizes[0] / 64;
    const int E = in_sizes[1] / 64;

    char* ws = (char*)d_ws;
    size_t off = 0;
    auto alloc = [&](size_t bytes) { size_t c = off; off += (bytes + 255) & ~(size_t)255; return c; };

    float*  agg      = (float*)(ws + alloc((size_t)N * 64 * 4));
    float*  deg      = (float*)(ws + alloc((size_t)N * 4));
    float*  edge_sum = (float*)(ws + alloc(256));
    float*  node_sum = (float*)(ws + alloc(256));
    size_t  zero_bytes = off;
    __bf16* nfb   = (__bf16*)(ws + alloc((size_t)N * 64 * 2));
    __bf16* ub    = (__bf16*)(ws + alloc(256));
    __bf16* wt1e  = (__bf16*)(ws + alloc(128 * 256 * 2));
    __bf16* wt2e  = (__bf16*)(ws + alloc(64 * 128 * 2));
    __bf16* wt1n  = (__bf16*)(ws + alloc(128 * 192 * 2));
    __bf16* wt2n  = (__bf16*)(ws + alloc(64 * 128 * 2));

    float* out_n = (float*)d_out;
    float* out_e = out_n + (size_t)N * 64;
    float* out_u = out_e + (size_t)E * 64;

    hipMemsetAsync(d_ws, 0, zero_bytes, stream);
    prep_nf<<<(N * 64 / 4 + 255) / 256, 256, 0, stream>>>(nf, nfb, N * 64);
    prep_w<<<(73792 + 255) / 256, 256, 0, stream>>>(eW1, eW2, nW1, nW2, u,
                                                    wt1e, wt2e, wt1n, wt2n, ub);
    edge_mfma<<<(E + 127) / 128, 256, 0, stream>>>(
        ef, nfb, ub, wt1e, wt2e, eb1, eb2, src, dst, out_e, agg, deg, E);
    node_mfma<<<(N + 127) / 128, 256, 0, stream>>>(
        nf, nfb, ub, wt1n, wt2n, nb1, nb2, agg, deg, out_n, node_sum, N);
    reduce_agg<<<128, 256, 0, stream>>>(agg, edge_sum, N);
    global_kernel<<<1, 128, 0, stream>>>(
        u, gW1, gb1, gW2, gb2, node_sum, edge_sum, out_u, N, E);
}